// Round 7
// baseline (2866.690 us; speedup 1.0000x reference)
//
#include <hip/hip_runtime.h>
#include <math.h>

// ---- problem constants ----
constexpr int B_ = 32, D_ = 512, H_ = 8, L_ = 8, MLP_ = 2048, NC_ = 3;
constexpr int P_ = 256;        // patches
constexpr int N_ = 257;        // tokens (P+1)
constexpr int HD_ = 64;        // head dim
constexpr int BP_ = B_ * P_;   // 8192 patch rows
constexpr int BN_ = B_ * N_;   // 8224 token rows
constexpr int MP_ = 8320;      // BN_ padded to 65*128 (=130*64)
constexpr int KP_ = 320;       // 5*8*8 im2col K
constexpr int NV_ = 288;       // padded n for V^T (9 k-chunks of 32)

enum { EPI_BIAS = 0, EPI_RES = 1, EPI_GELU = 2 };

using bf16x8 = __attribute__((ext_vector_type(8))) short;
using f32x4  = __attribute__((ext_vector_type(4))) float;

__device__ __forceinline__ float b2f(unsigned short u) {
    return __uint_as_float(((unsigned)u) << 16);
}
__device__ __forceinline__ unsigned short f2b(float f) {
    unsigned u = __float_as_uint(f);
    unsigned r = (u + 0x7FFFu + ((u >> 16) & 1u)) >> 16;  // RNE
    return (unsigned short)r;
}

__device__ __forceinline__ void gld_lds16(const void* g, void* l) {
    __builtin_amdgcn_global_load_lds(
        (const __attribute__((address_space(1))) void*)g,
        (__attribute__((address_space(3))) void*)l, 16, 0, 0);
}

// LDS byte-address for inline-asm ds ops (AS3 pointers are 32-bit offsets)
__device__ __forceinline__ unsigned lds_a(const void* p) {
    return (unsigned)(size_t)(const __attribute__((address_space(3))) void*)p;
}
// Opaque ds_read_b128 / global_load_dwordx4: invisible to the compiler's
// waitcnt pass so it cannot insert its own drains. Ordering is fully manual:
// counted vmcnt + raw s_barrier before, counted lgkmcnt + sched_barrier(0)
// after (rule 18).
__device__ __forceinline__ bf16x8 ds_read128(unsigned addr) {
    bf16x8 r;
    asm volatile("ds_read_b128 %0, %1" : "=v"(r) : "v"(addr));
    return r;
}
__device__ __forceinline__ bf16x8 gload128(unsigned long long addr) {
    bf16x8 r;
    asm volatile("global_load_dwordx4 %0, %1, off" : "=v"(r) : "v"(addr)
                 : "memory");
    return r;
}

// ---------------- im2col (bf16 out) ----------------
__global__ void im2col_k(const float* __restrict__ img,
                         unsigned short* __restrict__ X) {
    int idx = blockIdx.x * 256 + threadIdx.x;
    if (idx >= BP_ * KP_) return;
    int r = idx / KP_, j = idx % KP_;
    int b = r >> 8, p = r & 255;
    int py = p >> 4, px = p & 15;
    int c = j >> 6, kk = j & 63;
    int ky = kk >> 3, kx = kk & 7;
    const int dy[5] = {0, 1, -1, 1, -1};
    const int dx[5] = {0, 1, 1, -1, -1};
    int yy = (py * 8 + ky - dy[c] + 128) & 127;
    int xx = (px * 8 + kx - dx[c] + 128) & 127;
    X[idx] = f2b(img[b * 16384 + yy * 128 + xx]);
}

// ---------------- transpose + cast fp32 KxN -> bf16 NxK ----------------
__global__ __launch_bounds__(256) void castT_k(const float* __restrict__ in,
                                               unsigned short* __restrict__ out,
                                               int K, int N) {
    __shared__ float t[32][33];
    size_t loff = (size_t)blockIdx.z * K * N;
    int k0 = blockIdx.x * 32, n0 = blockIdx.y * 32;
    int tx = threadIdx.x & 31, ty = threadIdx.x >> 5;
    for (int i = ty; i < 32; i += 8)
        t[i][tx] = in[loff + (size_t)(k0 + i) * N + n0 + tx];
    __syncthreads();
    for (int i = ty; i < 32; i += 8)
        out[loff + (size_t)(n0 + i) * K + k0 + tx] = f2b(t[tx][i]);
}

// ---------------- plain cast ----------------
__global__ void cast_k(const float* __restrict__ in,
                       unsigned short* __restrict__ out, int n) {
    int idx = blockIdx.x * 256 + threadIdx.x;
    if (idx < n) out[idx] = f2b(in[idx]);
}

// ---------------- bf16 MFMA GEMM: C[M,N] = A[M,K] @ Bt[N,K]^T ----------------
// Round 11: r4-r6 all flat at ~56µs — LDS READ PIPE is the wall, not latency:
// 2.25 blk/CU x 16 ds_read_b128 x (12cy + 4cy conflict) > step budget, while
// MFMA/VALU/HBM sit idle. Counter proof: SQ_LDS_BANK_CONFLICT = 4.0 extra
// cy/read (old swizzle quad^(ra&3) only permutes same-parity chunk slots ->
// 4-way phase conflict). Fixes this round:
//  1) B operand DIRECT from global (L2-resident weight panel) into registers,
//     double-buffered one tile ahead via opaque global_load_dwordx4 — halves
//     ds_reads AND LDS-DMA writes; LDS drops to 20 KB (5 x 4KB A buffers).
//  2) swizzle quad^((ra>>1)&3) (store sj=(tid&3)^((srow>>1)&3)) -> 2-way=free.
//  3) depth-4 A staging, gate vmcnt(1) steady (drains stage(t+1)+B(t)),
//     vmcnt(0) in tails; one barrier/iter; reg-dbuf A frags kept.
__global__ __launch_bounds__(256, 6) void gemm_bf16_k(
    const unsigned short* __restrict__ A, const unsigned short* __restrict__ Bt,
    const float* __restrict__ bias, const float* __restrict__ res,
    float* __restrict__ outF, unsigned short* __restrict__ outB,
    int Nn, int K, int epi) {
    constexpr int BK = 32;
    constexpr int TSZ = 64 * BK * 2;            // 4096 B per tile buffer
    __shared__ unsigned short As[5][64 * BK];   // 5 x 4 KiB = 20 KiB
    int tid = threadIdx.x, lane = tid & 63;
    int wave = tid >> 6;
    int wrow = (wave >> 1) * 32, wcol = (wave & 1) * 32;

    // XCD-chunked bijective remap: each XCD gets a contiguous run of tiles.
    int gx = gridDim.x;
    int nwg = gx * (int)gridDim.y;
    int lid = blockIdx.y * gx + blockIdx.x;
    int qq = nwg >> 3, rr = nwg & 7;
    int xcd = lid & 7, loc = lid >> 3;
    int sid = (xcd < rr ? xcd * (qq + 1) : rr * (qq + 1) + (xcd - rr) * qq) + loc;
    size_t bm = (size_t)(sid / gx) * 64, bn = (size_t)(sid % gx) * 64;

    const unsigned short* Ab = A + bm * K;
    const unsigned short* Bb = Bt + bn * K;

    f32x4 acc[2][2] = {};
    int quad = lane >> 4, col = lane & 15;
    int NT = K / BK;  // EVEN (10/16/32/64) at every call site

    unsigned aB0 = lds_a(&As[0][0]);
    // per-wave A fragment byte offsets (2-way-conflict-free swizzle)
    unsigned aoff[2];
#pragma unroll
    for (int i = 0; i < 2; ++i) {
        int ra = wrow + i * 16 + col;
        aoff[i] = ra * (BK * 2) + ((quad ^ ((ra >> 1) & 3)) << 4);
    }
    // per-lane B global base addresses (advance by t*64 bytes per tile)
    unsigned long long bAddr[2];
#pragma unroll
    for (int i = 0; i < 2; ++i) {
        int rb = wcol + i * 16 + col;
        bAddr[i] = (unsigned long long)(Bb + (size_t)rb * K + quad * 8);
    }

    // stage one 64x32 A tile into buffer `buf`; 1 gld_lds per thread.
    int srow = tid >> 2;
    int sj = (tid & 3) ^ ((srow >> 1) & 3);  // matches read swizzle
    auto stage = [&](int buf, int t_) {
        gld_lds16(Ab + (size_t)srow * K + t_ * BK + sj * 8,
                  (char*)As[0] + buf * TSZ + tid * 16);
    };
    auto loadB = [&](bf16x8(&dst)[2], int t_) {
        unsigned long long o = (unsigned long long)t_ * (BK * 2);
        dst[0] = gload128(bAddr[0] + o);
        dst[1] = gload128(bAddr[1] + o);
    };

    bf16x8 a0[2], a1[2], vb0[2], vb1[2];

    // prologue: queue = [s0, B0, B0, s1, s2, s3]
    stage(0, 0);
    loadB(vb0, 0);
    stage(1, 1);
    stage(2, 2);
    stage(3, 3);
    asm volatile("s_waitcnt vmcnt(5)" ::: "memory");  // s0 landed
    __builtin_amdgcn_s_barrier();
    __builtin_amdgcn_sched_barrier(0);
#pragma unroll
    for (int i = 0; i < 2; ++i) a0[i] = ds_read128(aB0 + aoff[i]);  // tile 0

    for (int t = 0; t < NT; t += 2) {
        // ---- even sub-iter: compute tile t (a0/vb0); prefetch t+1 reads
        if (t + 3 < NT)
            asm volatile("s_waitcnt vmcnt(1)" ::: "memory");
        else
            asm volatile("s_waitcnt vmcnt(0)" ::: "memory");
        __builtin_amdgcn_s_barrier();
        __builtin_amdgcn_sched_barrier(0);
        loadB(vb1, t + 1);                       // B(t+1) -> set1
        if (t + 4 < NT) stage((t + 4) % 5, t + 4);
        {
            unsigned ab = aB0 + ((t + 1) % 5) * TSZ;
#pragma unroll
            for (int i = 0; i < 2; ++i) a1[i] = ds_read128(ab + aoff[i]);
        }
        asm volatile("s_waitcnt lgkmcnt(2)" ::: "memory");  // a0 ready
        __builtin_amdgcn_sched_barrier(0);
#pragma unroll
        for (int mi = 0; mi < 2; ++mi)
#pragma unroll
            for (int ni = 0; ni < 2; ++ni)
                acc[mi][ni] = __builtin_amdgcn_mfma_f32_16x16x32_bf16(
                    a0[mi], vb0[ni], acc[mi][ni], 0, 0, 0);
        __builtin_amdgcn_sched_barrier(0);

        // ---- odd sub-iter: compute tile t+1 (a1/vb1); prefetch t+2 reads
        int t1 = t + 1;
        if (t1 + 3 < NT)
            asm volatile("s_waitcnt vmcnt(1)" ::: "memory");
        else
            asm volatile("s_waitcnt vmcnt(0)" ::: "memory");
        __builtin_amdgcn_s_barrier();
        __builtin_amdgcn_sched_barrier(0);
        if (t1 + 1 < NT) {
            loadB(vb0, t1 + 1);                  // B(t+2) -> set0
            if (t1 + 4 < NT) stage((t1 + 4) % 5, t1 + 4);
            unsigned ab = aB0 + ((t1 + 1) % 5) * TSZ;
#pragma unroll
            for (int i = 0; i < 2; ++i) a0[i] = ds_read128(ab + aoff[i]);
            asm volatile("s_waitcnt lgkmcnt(2)" ::: "memory");  // a1 ready
        } else {
            asm volatile("s_waitcnt lgkmcnt(0)" ::: "memory");
        }
        __builtin_amdgcn_sched_barrier(0);
#pragma unroll
        for (int mi = 0; mi < 2; ++mi)
#pragma unroll
            for (int ni = 0; ni < 2; ++ni)
                acc[mi][ni] = __builtin_amdgcn_mfma_f32_16x16x32_bf16(
                    a1[mi], vb1[ni], acc[mi][ni], 0, 0, 0);
        __builtin_amdgcn_sched_barrier(0);
    }

#pragma unroll
    for (int mi = 0; mi < 2; ++mi) {
#pragma unroll
        for (int ni = 0; ni < 2; ++ni) {
            size_t gm0 = bm + wrow + mi * 16 + quad * 4;
            size_t gn = bn + wcol + ni * 16 + col;
            float bs = bias ? bias[gn] : 0.f;
#pragma unroll
            for (int r = 0; r < 4; ++r) {
                size_t o = (gm0 + r) * Nn + gn;
                float v = acc[mi][ni][r] + bs;
                if (epi == EPI_GELU)
                    v = 0.5f * v * (1.f + erff(v * 0.70710678118654752f));
                else if (epi == EPI_RES)
                    v += res[o];
                if (outF) outF[o] = v;
                if (outB) outB[o] = f2b(v);
            }
        }
    }
}

// ---------------- LayerNorm D=512, dual output (shuffle-reduce) ----------------
__global__ __launch_bounds__(256) void ln_k(
    const float* __restrict__ in, float* __restrict__ outF,
    unsigned short* __restrict__ outB, const float* __restrict__ g,
    const float* __restrict__ be, long instride, long ofs, long obs) {
    __shared__ float red[8];
    int row = blockIdx.x;
    const float2* x = (const float2*)(in + (size_t)row * instride);
    int t = threadIdx.x, lane = t & 63, wv = t >> 6;
    float2 v = x[t];
    float s = v.x + v.y;
#pragma unroll
    for (int m = 1; m < 64; m <<= 1) s += __shfl_xor(s, m);
    if (lane == 0) red[wv] = s;
    __syncthreads();
    float mu = (red[0] + red[1] + red[2] + red[3]) * (1.f / 512.f);
    float d0 = v.x - mu, d1 = v.y - mu;
    float q = d0 * d0 + d1 * d1;
#pragma unroll
    for (int m = 1; m < 64; m <<= 1) q += __shfl_xor(q, m);
    if (lane == 0) red[4 + wv] = q;
    __syncthreads();
    float rs =
        rsqrtf((red[4] + red[5] + red[6] + red[7]) * (1.f / 512.f) + 1e-5f);
    float2 gg = ((const float2*)g)[t];
    float2 bb = ((const float2*)be)[t];
    float y0 = d0 * rs * gg.x + bb.x;
    float y1 = d1 * rs * gg.y + bb.y;
    if (outF) {
        float2* y = (float2*)(outF + (size_t)row * ofs);
        y[t] = make_float2(y0, y1);
    }
    if (outB) {
        unsigned int p = (unsigned)f2b(y0) | ((unsigned)f2b(y1) << 16);
        ((unsigned int*)(outB + (size_t)row * obs))[t] = p;
    }
}

// ------- gate sigmoid + fuse + cls + pos_embed -> tokens (fp32, float4) -------
__global__ void assemble_k(const float* __restrict__ gatelin,
                           const float* __restrict__ src,
                           const float* __restrict__ orig,
                           const float* __restrict__ cls,
                           const float* __restrict__ pos,
                           float* __restrict__ tokens) {
    int idx = blockIdx.x * 256 + threadIdx.x;  // float4 granularity
    if (idx >= B_ * N_ * 128) return;
    int d4 = idx & 127;
    int bn = idx >> 7;
    int b = bn / N_, n = bn % N_;
    float4 pv = ((const float4*)pos)[n * 128 + d4];
    float4 v;
    if (n == 0) {
        v = ((const float4*)cls)[d4];
    } else {
        int r = b * 256 + (n - 1);
        float4 gl = ((const float4*)gatelin)[r * 128 + d4];
        float4 sv = ((const float4*)src)[r * 128 + d4];
        float4 ov = ((const float4*)orig)[r * 128 + d4];
        float g0 = 1.f / (1.f + expf(-gl.x));
        float g1 = 1.f / (1.f + expf(-gl.y));
        float g2 = 1.f / (1.f + expf(-gl.z));
        float g3 = 1.f / (1.f + expf(-gl.w));
        v.x = g0 * sv.x + (1.f - g0) * ov.x;
        v.y = g1 * sv.y + (1.f - g1) * ov.y;
        v.z = g2 * sv.z + (1.f - g2) * ov.z;
        v.w = g3 * sv.w + (1.f - g3) * ov.w;
    }
    v.x += pv.x; v.y += pv.y; v.z += pv.z; v.w += pv.w;
    ((float4*)tokens)[idx] = v;
}

// ---------------- V transpose: qkv -> Vt_g[bh][64][NV_] ----------------
__global__ __launch_bounds__(256) void vT_k(const unsigned short* __restrict__ qkv,
                                            unsigned short* __restrict__ Vt_g) {
    __shared__ unsigned short t[64][72];
    int bh = blockIdx.x, nt = blockIdx.y;
    int b = bh >> 3, h = bh & 7;
    int n0 = nt * 64;
    const unsigned short* vb = qkv + (size_t)(b * N_) * 1536 + 1024 + h * 64;
    int tid = threadIdx.x;
    for (int idx = tid; idx < 64 * 8; idx += 256) {
        int n = idx >> 3, c = idx & 7;
        int gn = n0 + n;
        uint4 u = {0, 0, 0, 0};
        if (gn < N_) u = *(const uint4*)(vb + (size_t)gn * 1536 + c * 8);
        *(uint4*)&t[n][c * 8] = u;
    }
    __syncthreads();
    for (int idx = tid; idx < 64 * 8; idx += 256) {
        int d = idx >> 3, j = idx & 7;
        if (n0 + j * 8 >= NV_) continue;
        unsigned short tmp[8];
#pragma unroll
        for (int e = 0; e < 8; ++e) tmp[e] = t[j * 8 + e][d];
        *(uint4*)&Vt_g[((size_t)bh * 64 + d) * NV_ + n0 + j * 8] =
            *(uint4*)tmp;
    }
}

// ---------------- fused flash attention v3: one wave per q-tile --------------
// grid: (bh=256, qg=5), 256 threads = 4 waves. FULLY UNROLLED so the score
// array s[18] stays in VGPRs — partial unroll forced it to scratch (round 4:
// 220 MB/dispatch spill writes, the real bottleneck).
__global__ __launch_bounds__(256) void attn_fused_k(
    const unsigned short* __restrict__ qkv,
    const unsigned short* __restrict__ Vt_g, const float* __restrict__ temp,
    unsigned short* __restrict__ obuf) {
    __shared__ __align__(16) unsigned short Ps[4][16][40];
    int bh = blockIdx.x;
    int b = bh >> 3, h = bh & 7;
    int tid = threadIdx.x, lane = tid & 63, wave = tid >> 6;
    int quad = lane >> 4, cid = lane & 15;
    int qt = blockIdx.y * 4 + wave;
    if (qt > 16) return;
    const unsigned short* qb = qkv + (size_t)(b * N_) * 1536 + h * 64;
    const unsigned short* kb = qb + 512;
    const unsigned short* vt = Vt_g + (size_t)bh * 64 * NV_;
    float tmp = temp[h];

    int qrow = qt * 16 + cid;
    if (qrow > 256) qrow = 256;
    bf16x8 aq0 = *(const bf16x8*)(qb + (size_t)qrow * 1536 + quad * 8);
    bf16x8 aq1 = *(const bf16x8*)(qb + (size_t)qrow * 1536 + 32 + quad * 8);

    f32x4 s[18];
#pragma unroll
    for (int t = 0; t < 17; ++t) {
        int krow = t * 16 + cid;
        if (t == 16 && krow > 256) krow = 256;  // static after full unroll
        const unsigned short* kp = kb + (size_t)krow * 1536 + quad * 8;
        bf16x8 bk0 = *(const bf16x8*)kp;
        bf16x8 bk1 = *(const bf16x8*)(kp + 32);
        f32x4 a = {0.f, 0.f, 0.f, 0.f};
        a = __builtin_amdgcn_mfma_f32_16x16x32_bf16(aq0, bk0, a, 0, 0, 0);
        a = __builtin_amdgcn_mfma_f32_16x16x32_bf16(aq1, bk1, a, 0, 0, 0);
        s[t] = a;
    }

    // mask + row max (rows = qt*16 + quad*4 + r, cols = t*16 + cid)
    float mx[4] = {-1e30f, -1e30f, -1e30f, -1e30f};
#pragma unroll
    for (int t = 0; t < 17; ++t) {
        int col = t * 16 + cid;
#pragma unroll
        for (int r = 0; r < 4; ++r) {
            int row = qt * 16 + quad * 4 + r;
            float v = s[t][r] * tmp;
            if (col == row || col >= 257) v = -1e30f;
            s[t][r] = v;
            mx[r] = fmaxf(mx[r], v);
        }
    }
    s[17] = f32x4{-1e30f, -1e30f, -1e30f, -1e30f};
#pragma unroll
    for (int m = 1; m < 16; m <<= 1)
#pragma unroll
        for (int r = 0; r < 4; ++r) mx[r] = fmaxf(mx[r], __shfl_xor(mx[r], m));
    float sum[4] = {0.f, 0.f, 0.f, 0.f};
#pragma unroll
    for (int t = 0; t < 18; ++t)
#pragma unroll
        for (int r = 0; r < 4; ++r) {
            float e = __expf(s[t][r] - mx[r]);
            float ef = b2f(f2b(e));
            s[t][r] = ef;
            sum[r] += ef;
        }
#pragma unroll
    for (int m = 1; m < 16; m <<= 1)
#pragma unroll
        for (int r = 0; r < 4; ++r) sum[r] += __shfl_xor(sum[r], m);
    float inv[4];
#pragma unroll
    for (int r = 0; r < 4; ++r) inv[r] = 1.f / sum[r];

    // PV: 9 k-chunks of 32 over n (fully unrolled, s[] stays in VGPRs)
    f32x4 o[4] = {};
#pragma unroll
    for (int kt = 0; kt < 9; ++kt) {
#pragma unroll
        for (int hh = 0; hh < 2; ++hh) {
            int t = kt * 2 + hh;
#pragma unroll
            for (int r = 0; r < 4; ++r)
                Ps[wave][quad * 4 + r][hh * 16 + cid] = f2b(s[t][r]);
        }
        bf16x8 ap = *(const bf16x8*)&Ps[wave][cid][quad * 8];
#pragma unroll
        for (int dt = 0; dt < 4; ++dt) {
            bf16x8 bv = *(const bf16x8*)(vt + (size_t)(dt * 16 + cid) * NV_ +
                                         kt * 32 + quad * 8);
            o[dt] =
                __builtin_amdgcn_mfma_f32_16x16x32_bf16(ap, bv, o[dt], 0, 0, 0);
        }
    }
#pragma unroll
    for (int dt = 0; dt < 4; ++dt)
#pragma unroll
        for (int r = 0; r < 4; ++r) {
            int row = qt * 16 + quad * 4 + r;
            if (row < N_)
                obuf[(size_t)(b * N_ + row) * 512 + h * 64 + dt * 16 + cid] =
                    f2b(o[dt][r] * inv[r]);
        }
}

// ------- head (fp32, tiny) -------
__global__ void head_k(const float* __restrict__ cls_out,
                       const float* __restrict__ hw,
                       const float* __restrict__ hb, float* __restrict__ out) {
    int t = threadIdx.x;
    if (t >= B_ * NC_) return;
    int b = t / NC_, c = t % NC_;
    float acc = hb[c];
    for (int d = 0; d < D_; ++d) acc += cls_out[b * D_ + d] * hw[d * NC_ + c];
    out[t] = acc;
}

extern "C" void kernel_launch(void* const* d_in, const int* in_sizes, int n_in,
                              void* d_out, int out_size, void* d_ws,
                              size_t ws_size, hipStream_t stream) {
    const float* image     = (const float*)d_in[0];
    const float* ssw       = (const float*)d_in[1];
    const float* ssb       = (const float*)d_in[2];
    const float* ssg       = (const float*)d_in[3];
    const float* ssbeta    = (const float*)d_in[4];
    const float* sow       = (const float*)d_in[5];
    const float* sob       = (const float*)d_in[6];
    const float* sog       = (const float*)d_in[7];
    const float* sobeta    = (const float*)d_in[8];
    const float* fw        = (const float*)d_in[9];
    const float* fb        = (const float*)d_in[10];
    const float* cls_token = (const float*)d_in[11];
    const float* pos_embed = (const float*)d_in[12];
    const float* ln1g      = (const float*)d_in[13];
    const float* ln1b      = (const float*)d_in[14];
    const float* qkvw      = (const float*)d_in[15];
    const float* qkvb      = (const float*)d_in[16];
    const float* projw     = (const float*)d_in[17];
    const float* projb     = (const float*)d_in[18];
    const float* temp      = (const float*)d_in[19];
    const float* ln2g      = (const float*)d_in[20];
    const float* ln2b      = (const float*)d_in[21];
    const float* w1        = (const float*)d_in[22];
    const float* b1        = (const float*)d_in[23];
    const float* w2        = (const float*)d_in[24];
    const float* b2        = (const float*)d_in[25];
    const float* ng        = (const float*)d_in[26];
    const float* nb        = (const float*)d_in[27];
    const float* hw        = (const float*)d_in[28];
    const float* hb        = (const float*)d_in[29];
    float* out = (float*)d_out;

    char* w = (char*)d_ws;
    size_t off = 0;
    float* tokens = (float*)w;                           off += (size_t)MP_ * 512 * 4;
    unsigned short* qkvw_t = (unsigned short*)(w + off); off += (size_t)8 * 1536 * 512 * 2;
    unsigned short* projw_t = (unsigned short*)(w + off); off += (size_t)8 * 512 * 512 * 2;
    unsigned short* w1_t = (unsigned short*)(w + off);   off += (size_t)8 * 2048 * 512 * 2;
    unsigned short* w2_t = (unsigned short*)(w + off);   off += (size_t)8 * 512 * 2048 * 2;
    unsigned short* fw_t = (unsigned short*)(w + off);   off += (size_t)512 * 1024 * 2;
    unsigned short* sswb = (unsigned short*)(w + off);   off += (size_t)512 * 320 * 2;
    unsigned short* sowb = (unsigned short*)(w + off);   off += (size_t)512 * 320 * 2;
    char* S = w + off;

    // prestage aliases (dead after assemble_k)
    unsigned short* Xb   = (unsigned short*)S;
    float* srct          = (float*)(S + 5242880);
    float* origt         = (float*)(S + 5242880 + 16777216);
    unsigned short* comb = (unsigned short*)(S + 5242880 + 2 * 16777216);
    float* gatelin       = (float*)(S + 5242880 + 3 * 16777216);

    // per-layer aliases
    unsigned short* xbuf = (unsigned short*)S;                      // 8,519,680
    unsigned short* qkvB = (unsigned short*)(S + 8519680);          // 25,559,040
    unsigned short* obuf = (unsigned short*)(S + 8519680 + 25559040);            // 8,519,680
    unsigned short* hbuf = (unsigned short*)(S + 8519680 + 25559040 + 8519680);  // 34,078,720
    unsigned short* vt_g = (unsigned short*)(S + 8519680 + 25559040 + 8519680 +
                                             34078720);             // 9,437,184
    float* cls_out = (float*)(S + 8519680 + 25559040 + 8519680 + 34078720 +
                              9437184);

    // ---- weight casts/transposes (bf16, N x K) ----
    castT_k<<<dim3(16, 48, 8), 256, 0, stream>>>(qkvw, qkvw_t, 512, 1536);
    castT_k<<<dim3(16, 16, 8), 256, 0, stream>>>(projw, projw_t, 512, 512);
    castT_k<<<dim3(16, 64, 8), 256, 0, stream>>>(w1, w1_t, 512, 2048);
    castT_k<<<dim3(64, 16, 8), 256, 0, stream>>>(w2, w2_t, 2048, 512);
    castT_k<<<dim3(32, 16, 1), 256, 0, stream>>>(fw, fw_t, 1024, 512);
    cast_k<<<640, 256, 0, stream>>>(ssw, sswb, 512 * 320);
    cast_k<<<640, 256, 0, stream>>>(sow, sowb, 512 * 320);

    // ---- SPT ----
    im2col_k<<<(BP_ * KP_ + 255) / 256, 256, 0, stream>>>(image, Xb);
    dim3 gspt(8, 128);
    gemm_bf16_k<<<gspt, 256, 0, stream>>>(Xb, sswb, ssb, nullptr, srct, nullptr,
                                          512, KP_, EPI_BIAS);
    ln_k<<<BP_, 256, 0, stream>>>(srct, srct, comb, ssg, ssbeta, 512, 512, 1024);
    gemm_bf16_k<<<gspt, 256, 0, stream>>>(Xb, sowb, sob, nullptr, origt, nullptr,
                                          512, KP_, EPI_BIAS);
    ln_k<<<BP_, 256, 0, stream>>>(origt, origt, comb + 512, sog, sobeta, 512,
                                  512, 1024);
    // ---- gated fusion ----
    gemm_bf16_k<<<gspt, 256, 0, stream>>>(comb, fw_t, fb, nullptr, gatelin,
                                          nullptr, 512, 1024, EPI_BIAS);
    assemble_k<<<(B_ * N_ * 128 + 255) / 256, 256, 0, stream>>>(
        gatelin, srct, origt, cls_token, pos_embed, tokens);

    // ---- transformer layers ----
    dim3 gqkv(24, 130), gproj(8, 130), gfc1(32, 130);
    for (int l = 0; l < L_; ++l) {
        const float* l1g = ln1g + l * D_;
        const float* l1b = ln1b + l * D_;
        const unsigned short* qw = qkvw_t + (size_t)l * 1536 * 512;
        const float* qb  = qkvb + (size_t)l * 3 * D_;
        const unsigned short* pw = projw_t + (size_t)l * 512 * 512;
        const float* pb  = projb + (size_t)l * D_;
        const float* tp  = temp + l * H_;
        const float* l2g = ln2g + l * D_;
        const float* l2b = ln2b + l * D_;
        const unsigned short* w1l = w1_t + (size_t)l * 2048 * 512;
        const float* b1l = b1 + (size_t)l * MLP_;
        const unsigned short* w2l = w2_t + (size_t)l * 512 * 2048;
        const float* b2l = b2 + (size_t)l * D_;

        ln_k<<<BN_, 256, 0, stream>>>(tokens, nullptr, xbuf, l1g, l1b, 512, 0,
                                      512);
        gemm_bf16_k<<<gqkv, 256, 0, stream>>>(xbuf, qw, qb, nullptr, nullptr,
                                              qkvB, 1536, 512, EPI_BIAS);
        vT_k<<<dim3(256, 5), 256, 0, stream>>>(qkvB, vt_g);
        attn_fused_k<<<dim3(256, 5), 256, 0, stream>>>(qkvB, vt_g, tp, obuf);
        gemm_bf16_k<<<gproj, 256, 0, stream>>>(obuf, pw, pb, tokens, tokens,
                                               nullptr, 512, 512, EPI_RES);
        ln_k<<<BN_, 256, 0, stream>>>(tokens, nullptr, xbuf, l2g, l2b, 512, 0,
                                      512);
        gemm_bf16_k<<<gfc1, 256, 0, stream>>>(xbuf, w1l, b1l, nullptr, nullptr,
                                              hbuf, 2048, 512, EPI_GELU);
        gemm_bf16_k<<<gproj, 256, 0, stream>>>(hbuf, w2l, b2l, tokens, tokens,
                                               nullptr, 512, 2048, EPI_RES);
    }

    // ---- final LN on cls token + head ----
    ln_k<<<B_, 256, 0, stream>>>(tokens, cls_out, nullptr, ng, nb,
                                 (long)N_ * 512, 512, 0);
    head_k<<<1, 128, 0, stream>>>(cls_out, hw, hb, out);
}

// Round 8
// 1958.499 us; speedup vs baseline: 1.4637x; 1.4637x over previous
//
#include <hip/hip_runtime.h>
#include <math.h>

// ---- problem constants ----
constexpr int B_ = 32, D_ = 512, H_ = 8, L_ = 8, MLP_ = 2048, NC_ = 3;
constexpr int P_ = 256;        // patches
constexpr int N_ = 257;        // tokens (P+1)
constexpr int HD_ = 64;        // head dim
constexpr int BP_ = B_ * P_;   // 8192 patch rows
constexpr int BN_ = B_ * N_;   // 8224 token rows
constexpr int MP_ = 8320;      // BN_ padded to 65*128
constexpr int KP_ = 320;       // 5*8*8 im2col K
constexpr int NV_ = 288;       // padded n for V^T (9 k-chunks of 32)

enum { EPI_BIAS = 0, EPI_RES = 1, EPI_GELU = 2 };

using bf16x8 = __attribute__((ext_vector_type(8))) short;
using f32x4  = __attribute__((ext_vector_type(4))) float;

__device__ __forceinline__ float b2f(unsigned short u) {
    return __uint_as_float(((unsigned)u) << 16);
}
__device__ __forceinline__ unsigned short f2b(float f) {
    unsigned u = __float_as_uint(f);
    unsigned r = (u + 0x7FFFu + ((u >> 16) & 1u)) >> 16;  // RNE
    return (unsigned short)r;
}

__device__ __forceinline__ void gld_lds16(const void* g, void* l) {
    __builtin_amdgcn_global_load_lds(
        (const __attribute__((address_space(1))) void*)g,
        (__attribute__((address_space(3))) void*)l, 16, 0, 0);
}

// LDS byte-address for inline-asm ds ops (AS3 pointers are 32-bit offsets)
__device__ __forceinline__ unsigned lds_a(const void* p) {
    return (unsigned)(size_t)(const __attribute__((address_space(3))) void*)p;
}
// Opaque ds_read_b128: invisible to the compiler's waitcnt pass so it cannot
// insert its own s_waitcnt vmcnt(0) ordering LDS-DMA vs this read. Ordering
// is fully manual (rule 18).
__device__ __forceinline__ bf16x8 ds_read128(unsigned addr) {
    bf16x8 r;
    asm volatile("ds_read_b128 %0, %1" : "=v"(r) : "v"(addr));
    return r;
}

// ---------------- im2col (bf16 out) ----------------
__global__ void im2col_k(const float* __restrict__ img,
                         unsigned short* __restrict__ X) {
    int idx = blockIdx.x * 256 + threadIdx.x;
    if (idx >= BP_ * KP_) return;
    int r = idx / KP_, j = idx % KP_;
    int b = r >> 8, p = r & 255;
    int py = p >> 4, px = p & 15;
    int c = j >> 6, kk = j & 63;
    int ky = kk >> 3, kx = kk & 7;
    const int dy[5] = {0, 1, -1, 1, -1};
    const int dx[5] = {0, 1, 1, -1, -1};
    int yy = (py * 8 + ky - dy[c] + 128) & 127;
    int xx = (px * 8 + kx - dx[c] + 128) & 127;
    X[idx] = f2b(img[b * 16384 + yy * 128 + xx]);
}

// ---------------- transpose + cast fp32 KxN -> bf16 NxK ----------------
__global__ __launch_bounds__(256) void castT_k(const float* __restrict__ in,
                                               unsigned short* __restrict__ out,
                                               int K, int N) {
    __shared__ float t[32][33];
    size_t loff = (size_t)blockIdx.z * K * N;
    int k0 = blockIdx.x * 32, n0 = blockIdx.y * 32;
    int tx = threadIdx.x & 31, ty = threadIdx.x >> 5;
    for (int i = ty; i < 32; i += 8)
        t[i][tx] = in[loff + (size_t)(k0 + i) * N + n0 + tx];
    __syncthreads();
    for (int i = ty; i < 32; i += 8)
        out[loff + (size_t)(n0 + i) * K + k0 + tx] = f2b(t[tx][i]);
}

// ---------------- plain cast ----------------
__global__ void cast_k(const float* __restrict__ in,
                       unsigned short* __restrict__ out, int n) {
    int idx = blockIdx.x * 256 + threadIdx.x;
    if (idx < n) out[idx] = f2b(in[idx]);
}

// ---------------- bf16 MFMA GEMM: C[M,N] = A[M,K] @ Bt[N,K]^T ----------------
// Round 12: r7 post-mortem — swizzle fix verified (conflicts 4.26M -> 0) but
// B-from-global gather regressed badly (TA address throughput + L2 latency
// exposed). Revert B to LDS-DMA; keep fixed swizzle. The standing limiter is
// work:overhead of the register tile (4 MFMA per 4 reads per ~500cy step ->
// MfmaUtil 11%). This round: 128x64 block tile, wave = 64x32 (acc[4][2]):
// 8 MFMA from 6 ds_reads per step (+33% FLOP/LDS-byte, 2x MFMA per step
// overhead). Schedule = r4's (the best-total round): 3 buffers, counted
// vmcnt(3), ONE barrier/step, stage-after-reads depth-2, lgkmcnt(0), no
// setprio, no reg-dbuf. LDS 3 x 12KB = 36KB -> 4 blocks/CU cap.
__global__ __launch_bounds__(256, 4) void gemm_bf16_k(
    const unsigned short* __restrict__ A, const unsigned short* __restrict__ Bt,
    const float* __restrict__ bias, const float* __restrict__ res,
    float* __restrict__ outF, unsigned short* __restrict__ outB,
    int Nn, int K, int epi) {
    constexpr int BK = 32;
    constexpr int ASZ = 128 * BK * 2;  // 8 KiB A tile
    constexpr int BSZ = 64 * BK * 2;   // 4 KiB B tile
    __shared__ unsigned short As[3][128 * BK];  // 3 x 8 KiB
    __shared__ unsigned short Bs[3][64 * BK];   // 3 x 4 KiB (36 KiB total)
    int tid = threadIdx.x, lane = tid & 63;
    int wave = tid >> 6;
    int wrow = (wave >> 1) * 64, wcol = (wave & 1) * 32;

    // XCD-chunked bijective remap: each XCD gets a contiguous run of tiles.
    int gx = gridDim.x;
    int nwg = gx * (int)gridDim.y;
    int lid = blockIdx.y * gx + blockIdx.x;
    int qq = nwg >> 3, rr = nwg & 7;
    int xcd = lid & 7, loc = lid >> 3;
    int sid = (xcd < rr ? xcd * (qq + 1) : rr * (qq + 1) + (xcd - rr) * qq) + loc;
    size_t bm = (size_t)(sid / gx) * 128, bn = (size_t)(sid % gx) * 64;

    const unsigned short* Ab = A + bm * K;
    const unsigned short* Bb = Bt + bn * K;

    f32x4 acc[4][2] = {};
    int quad = lane >> 4, col = lane & 15;
    int NT = K / BK;

    unsigned aB0 = lds_a(&As[0][0]);
    unsigned bB0 = lds_a(&Bs[0][0]);
    // fragment byte offsets, conflict-free swizzle (r7-verified): chunk slot
    // quad ^ ((row>>1)&3), matching store side.
    unsigned aoff[4], boff[2];
#pragma unroll
    for (int i = 0; i < 4; ++i) {
        int ra = wrow + i * 16 + col;
        aoff[i] = ra * (BK * 2) + ((quad ^ ((ra >> 1) & 3)) << 4);
    }
#pragma unroll
    for (int j = 0; j < 2; ++j) {
        int rb = wcol + j * 16 + col;
        boff[j] = rb * (BK * 2) + ((quad ^ ((rb >> 1) & 3)) << 4);
    }

    // stage one 128x32 A + 64x32 B tile pair; 3 gld_lds per thread.
    auto stage = [&](int buf, int t_) {
#pragma unroll
        for (int it = 0; it < 2; ++it) {
            int c = it * 256 + tid;
            int row = c >> 2, sj = (c & 3) ^ ((row >> 1) & 3);
            gld_lds16(Ab + (size_t)row * K + t_ * BK + sj * 8,
                      (char*)As[0] + buf * ASZ + c * 16);
        }
        int brow = tid >> 2, bj = (tid & 3) ^ ((brow >> 1) & 3);
        gld_lds16(Bb + (size_t)brow * K + t_ * BK + bj * 8,
                  (char*)Bs[0] + buf * BSZ + tid * 16);
    };

    stage(0, 0);
    if (NT > 1) stage(1, 1);
    for (int t = 0; t < NT; ++t) {
        int cur = t % 3;
        if (t + 1 < NT)
            asm volatile("s_waitcnt vmcnt(3)" ::: "memory");  // tile t landed
        else
            asm volatile("s_waitcnt vmcnt(0)" ::: "memory");
        __builtin_amdgcn_s_barrier();
        __builtin_amdgcn_sched_barrier(0);
        unsigned aB = aB0 + cur * ASZ;
        unsigned bB = bB0 + cur * BSZ;
        bf16x8 af[4], bfr[2];
#pragma unroll
        for (int i = 0; i < 4; ++i) af[i] = ds_read128(aB + aoff[i]);
#pragma unroll
        for (int j = 0; j < 2; ++j) bfr[j] = ds_read128(bB + boff[j]);
        if (t + 2 < NT) stage((t + 2) % 3, t + 2);  // depth-2, post-reads
        asm volatile("s_waitcnt lgkmcnt(0)" ::: "memory");
        __builtin_amdgcn_sched_barrier(0);
#pragma unroll
        for (int mi = 0; mi < 4; ++mi)
#pragma unroll
            for (int ni = 0; ni < 2; ++ni)
                acc[mi][ni] = __builtin_amdgcn_mfma_f32_16x16x32_bf16(
                    af[mi], bfr[ni], acc[mi][ni], 0, 0, 0);
        __builtin_amdgcn_sched_barrier(0);  // pin reads+MFMA inside the iter
    }

#pragma unroll
    for (int mi = 0; mi < 4; ++mi) {
#pragma unroll
        for (int ni = 0; ni < 2; ++ni) {
            size_t gm0 = bm + wrow + mi * 16 + quad * 4;
            size_t gn = bn + wcol + ni * 16 + col;
            float bs = bias ? bias[gn] : 0.f;
#pragma unroll
            for (int r = 0; r < 4; ++r) {
                size_t o = (gm0 + r) * Nn + gn;
                float v = acc[mi][ni][r] + bs;
                if (epi == EPI_GELU)
                    v = 0.5f * v * (1.f + erff(v * 0.70710678118654752f));
                else if (epi == EPI_RES)
                    v += res[o];
                if (outF) outF[o] = v;
                if (outB) outB[o] = f2b(v);
            }
        }
    }
}

// ---------------- LayerNorm D=512, dual output (shuffle-reduce) ----------------
__global__ __launch_bounds__(256) void ln_k(
    const float* __restrict__ in, float* __restrict__ outF,
    unsigned short* __restrict__ outB, const float* __restrict__ g,
    const float* __restrict__ be, long instride, long ofs, long obs) {
    __shared__ float red[8];
    int row = blockIdx.x;
    const float2* x = (const float2*)(in + (size_t)row * instride);
    int t = threadIdx.x, lane = t & 63, wv = t >> 6;
    float2 v = x[t];
    float s = v.x + v.y;
#pragma unroll
    for (int m = 1; m < 64; m <<= 1) s += __shfl_xor(s, m);
    if (lane == 0) red[wv] = s;
    __syncthreads();
    float mu = (red[0] + red[1] + red[2] + red[3]) * (1.f / 512.f);
    float d0 = v.x - mu, d1 = v.y - mu;
    float q = d0 * d0 + d1 * d1;
#pragma unroll
    for (int m = 1; m < 64; m <<= 1) q += __shfl_xor(q, m);
    if (lane == 0) red[4 + wv] = q;
    __syncthreads();
    float rs =
        rsqrtf((red[4] + red[5] + red[6] + red[7]) * (1.f / 512.f) + 1e-5f);
    float2 gg = ((const float2*)g)[t];
    float2 bb = ((const float2*)be)[t];
    float y0 = d0 * rs * gg.x + bb.x;
    float y1 = d1 * rs * gg.y + bb.y;
    if (outF) {
        float2* y = (float2*)(outF + (size_t)row * ofs);
        y[t] = make_float2(y0, y1);
    }
    if (outB) {
        unsigned int p = (unsigned)f2b(y0) | ((unsigned)f2b(y1) << 16);
        ((unsigned int*)(outB + (size_t)row * obs))[t] = p;
    }
}

// ------- gate sigmoid + fuse + cls + pos_embed -> tokens (fp32, float4) -------
__global__ void assemble_k(const float* __restrict__ gatelin,
                           const float* __restrict__ src,
                           const float* __restrict__ orig,
                           const float* __restrict__ cls,
                           const float* __restrict__ pos,
                           float* __restrict__ tokens) {
    int idx = blockIdx.x * 256 + threadIdx.x;  // float4 granularity
    if (idx >= B_ * N_ * 128) return;
    int d4 = idx & 127;
    int bn = idx >> 7;
    int b = bn / N_, n = bn % N_;
    float4 pv = ((const float4*)pos)[n * 128 + d4];
    float4 v;
    if (n == 0) {
        v = ((const float4*)cls)[d4];
    } else {
        int r = b * 256 + (n - 1);
        float4 gl = ((const float4*)gatelin)[r * 128 + d4];
        float4 sv = ((const float4*)src)[r * 128 + d4];
        float4 ov = ((const float4*)orig)[r * 128 + d4];
        float g0 = 1.f / (1.f + expf(-gl.x));
        float g1 = 1.f / (1.f + expf(-gl.y));
        float g2 = 1.f / (1.f + expf(-gl.z));
        float g3 = 1.f / (1.f + expf(-gl.w));
        v.x = g0 * sv.x + (1.f - g0) * ov.x;
        v.y = g1 * sv.y + (1.f - g1) * ov.y;
        v.z = g2 * sv.z + (1.f - g2) * ov.z;
        v.w = g3 * sv.w + (1.f - g3) * ov.w;
    }
    v.x += pv.x; v.y += pv.y; v.z += pv.z; v.w += pv.w;
    ((float4*)tokens)[idx] = v;
}

// ---------------- V transpose: qkv -> Vt_g[bh][64][NV_] ----------------
__global__ __launch_bounds__(256) void vT_k(const unsigned short* __restrict__ qkv,
                                            unsigned short* __restrict__ Vt_g) {
    __shared__ unsigned short t[64][72];
    int bh = blockIdx.x, nt = blockIdx.y;
    int b = bh >> 3, h = bh & 7;
    int n0 = nt * 64;
    const unsigned short* vb = qkv + (size_t)(b * N_) * 1536 + 1024 + h * 64;
    int tid = threadIdx.x;
    for (int idx = tid; idx < 64 * 8; idx += 256) {
        int n = idx >> 3, c = idx & 7;
        int gn = n0 + n;
        uint4 u = {0, 0, 0, 0};
        if (gn < N_) u = *(const uint4*)(vb + (size_t)gn * 1536 + c * 8);
        *(uint4*)&t[n][c * 8] = u;
    }
    __syncthreads();
    for (int idx = tid; idx < 64 * 8; idx += 256) {
        int d = idx >> 3, j = idx & 7;
        if (n0 + j * 8 >= NV_) continue;
        unsigned short tmp[8];
#pragma unroll
        for (int e = 0; e < 8; ++e) tmp[e] = t[j * 8 + e][d];
        *(uint4*)&Vt_g[((size_t)bh * 64 + d) * NV_ + n0 + j * 8] =
            *(uint4*)tmp;
    }
}

// ---------------- fused flash attention v3: one wave per q-tile --------------
// grid: (bh=256, qg=5), 256 threads = 4 waves. FULLY UNROLLED so the score
// array s[18] stays in VGPRs — partial unroll forced it to scratch (round 4:
// 220 MB/dispatch spill writes, the real bottleneck).
__global__ __launch_bounds__(256) void attn_fused_k(
    const unsigned short* __restrict__ qkv,
    const unsigned short* __restrict__ Vt_g, const float* __restrict__ temp,
    unsigned short* __restrict__ obuf) {
    __shared__ __align__(16) unsigned short Ps[4][16][40];
    int bh = blockIdx.x;
    int b = bh >> 3, h = bh & 7;
    int tid = threadIdx.x, lane = tid & 63, wave = tid >> 6;
    int quad = lane >> 4, cid = lane & 15;
    int qt = blockIdx.y * 4 + wave;
    if (qt > 16) return;
    const unsigned short* qb = qkv + (size_t)(b * N_) * 1536 + h * 64;
    const unsigned short* kb = qb + 512;
    const unsigned short* vt = Vt_g + (size_t)bh * 64 * NV_;
    float tmp = temp[h];

    int qrow = qt * 16 + cid;
    if (qrow > 256) qrow = 256;
    bf16x8 aq0 = *(const bf16x8*)(qb + (size_t)qrow * 1536 + quad * 8);
    bf16x8 aq1 = *(const bf16x8*)(qb + (size_t)qrow * 1536 + 32 + quad * 8);

    f32x4 s[18];
#pragma unroll
    for (int t = 0; t < 17; ++t) {
        int krow = t * 16 + cid;
        if (t == 16 && krow > 256) krow = 256;  // static after full unroll
        const unsigned short* kp = kb + (size_t)krow * 1536 + quad * 8;
        bf16x8 bk0 = *(const bf16x8*)kp;
        bf16x8 bk1 = *(const bf16x8*)(kp + 32);
        f32x4 a = {0.f, 0.f, 0.f, 0.f};
        a = __builtin_amdgcn_mfma_f32_16x16x32_bf16(aq0, bk0, a, 0, 0, 0);
        a = __builtin_amdgcn_mfma_f32_16x16x32_bf16(aq1, bk1, a, 0, 0, 0);
        s[t] = a;
    }

    // mask + row max (rows = qt*16 + quad*4 + r, cols = t*16 + cid)
    float mx[4] = {-1e30f, -1e30f, -1e30f, -1e30f};
#pragma unroll
    for (int t = 0; t < 17; ++t) {
        int col = t * 16 + cid;
#pragma unroll
        for (int r = 0; r < 4; ++r) {
            int row = qt * 16 + quad * 4 + r;
            float v = s[t][r] * tmp;
            if (col == row || col >= 257) v = -1e30f;
            s[t][r] = v;
            mx[r] = fmaxf(mx[r], v);
        }
    }
    s[17] = f32x4{-1e30f, -1e30f, -1e30f, -1e30f};
#pragma unroll
    for (int m = 1; m < 16; m <<= 1)
#pragma unroll
        for (int r = 0; r < 4; ++r) mx[r] = fmaxf(mx[r], __shfl_xor(mx[r], m));
    float sum[4] = {0.f, 0.f, 0.f, 0.f};
#pragma unroll
    for (int t = 0; t < 18; ++t)
#pragma unroll
        for (int r = 0; r < 4; ++r) {
            float e = __expf(s[t][r] - mx[r]);
            float ef = b2f(f2b(e));
            s[t][r] = ef;
            sum[r] += ef;
        }
#pragma unroll
    for (int m = 1; m < 16; m <<= 1)
#pragma unroll
        for (int r = 0; r < 4; ++r) sum[r] += __shfl_xor(sum[r], m);
    float inv[4];
#pragma unroll
    for (int r = 0; r < 4; ++r) inv[r] = 1.f / sum[r];

    // PV: 9 k-chunks of 32 over n (fully unrolled, s[] stays in VGPRs)
    f32x4 o[4] = {};
#pragma unroll
    for (int kt = 0; kt < 9; ++kt) {
#pragma unroll
        for (int hh = 0; hh < 2; ++hh) {
            int t = kt * 2 + hh;
#pragma unroll
            for (int r = 0; r < 4; ++r)
                Ps[wave][quad * 4 + r][hh * 16 + cid] = f2b(s[t][r]);
        }
        bf16x8 ap = *(const bf16x8*)&Ps[wave][cid][quad * 8];
#pragma unroll
        for (int dt = 0; dt < 4; ++dt) {
            bf16x8 bv = *(const bf16x8*)(vt + (size_t)(dt * 16 + cid) * NV_ +
                                         kt * 32 + quad * 8);
            o[dt] =
                __builtin_amdgcn_mfma_f32_16x16x32_bf16(ap, bv, o[dt], 0, 0, 0);
        }
    }
#pragma unroll
    for (int dt = 0; dt < 4; ++dt)
#pragma unroll
        for (int r = 0; r < 4; ++r) {
            int row = qt * 16 + quad * 4 + r;
            if (row < N_)
                obuf[(size_t)(b * N_ + row) * 512 + h * 64 + dt * 16 + cid] =
                    f2b(o[dt][r] * inv[r]);
        }
}

// ------- head (fp32, tiny) -------
__global__ void head_k(const float* __restrict__ cls_out,
                       const float* __restrict__ hw,
                       const float* __restrict__ hb, float* __restrict__ out) {
    int t = threadIdx.x;
    if (t >= B_ * NC_) return;
    int b = t / NC_, c = t % NC_;
    float acc = hb[c];
    for (int d = 0; d < D_; ++d) acc += cls_out[b * D_ + d] * hw[d * NC_ + c];
    out[t] = acc;
}

extern "C" void kernel_launch(void* const* d_in, const int* in_sizes, int n_in,
                              void* d_out, int out_size, void* d_ws,
                              size_t ws_size, hipStream_t stream) {
    const float* image     = (const float*)d_in[0];
    const float* ssw       = (const float*)d_in[1];
    const float* ssb       = (const float*)d_in[2];
    const float* ssg       = (const float*)d_in[3];
    const float* ssbeta    = (const float*)d_in[4];
    const float* sow       = (const float*)d_in[5];
    const float* sob       = (const float*)d_in[6];
    const float* sog       = (const float*)d_in[7];
    const float* sobeta    = (const float*)d_in[8];
    const float* fw        = (const float*)d_in[9];
    const float* fb        = (const float*)d_in[10];
    const float* cls_token = (const float*)d_in[11];
    const float* pos_embed = (const float*)d_in[12];
    const float* ln1g      = (const float*)d_in[13];
    const float* ln1b      = (const float*)d_in[14];
    const float* qkvw      = (const float*)d_in[15];
    const float* qkvb      = (const float*)d_in[16];
    const float* projw     = (const float*)d_in[17];
    const float* projb     = (const float*)d_in[18];
    const float* temp      = (const float*)d_in[19];
    const float* ln2g      = (const float*)d_in[20];
    const float* ln2b      = (const float*)d_in[21];
    const float* w1        = (const float*)d_in[22];
    const float* b1        = (const float*)d_in[23];
    const float* w2        = (const float*)d_in[24];
    const float* b2        = (const float*)d_in[25];
    const float* ng        = (const float*)d_in[26];
    const float* nb        = (const float*)d_in[27];
    const float* hw        = (const float*)d_in[28];
    const float* hb        = (const float*)d_in[29];
    float* out = (float*)d_out;

    char* w = (char*)d_ws;
    size_t off = 0;
    float* tokens = (float*)w;                           off += (size_t)MP_ * 512 * 4;
    unsigned short* qkvw_t = (unsigned short*)(w + off); off += (size_t)8 * 1536 * 512 * 2;
    unsigned short* projw_t = (unsigned short*)(w + off); off += (size_t)8 * 512 * 512 * 2;
    unsigned short* w1_t = (unsigned short*)(w + off);   off += (size_t)8 * 2048 * 512 * 2;
    unsigned short* w2_t = (unsigned short*)(w + off);   off += (size_t)8 * 512 * 2048 * 2;
    unsigned short* fw_t = (unsigned short*)(w + off);   off += (size_t)512 * 1024 * 2;
    unsigned short* sswb = (unsigned short*)(w + off);   off += (size_t)512 * 320 * 2;
    unsigned short* sowb = (unsigned short*)(w + off);   off += (size_t)512 * 320 * 2;
    char* S = w + off;

    // prestage aliases (dead after assemble_k)
    unsigned short* Xb   = (unsigned short*)S;
    float* srct          = (float*)(S + 5242880);
    float* origt         = (float*)(S + 5242880 + 16777216);
    unsigned short* comb = (unsigned short*)(S + 5242880 + 2 * 16777216);
    float* gatelin       = (float*)(S + 5242880 + 3 * 16777216);

    // per-layer aliases
    unsigned short* xbuf = (unsigned short*)S;                      // 8,519,680
    unsigned short* qkvB = (unsigned short*)(S + 8519680);          // 25,559,040
    unsigned short* obuf = (unsigned short*)(S + 8519680 + 25559040);            // 8,519,680
    unsigned short* hbuf = (unsigned short*)(S + 8519680 + 25559040 + 8519680);  // 34,078,720
    unsigned short* vt_g = (unsigned short*)(S + 8519680 + 25559040 + 8519680 +
                                             34078720);             // 9,437,184
    float* cls_out = (float*)(S + 8519680 + 25559040 + 8519680 + 34078720 +
                              9437184);

    // ---- weight casts/transposes (bf16, N x K) ----
    castT_k<<<dim3(16, 48, 8), 256, 0, stream>>>(qkvw, qkvw_t, 512, 1536);
    castT_k<<<dim3(16, 16, 8), 256, 0, stream>>>(projw, projw_t, 512, 512);
    castT_k<<<dim3(16, 64, 8), 256, 0, stream>>>(w1, w1_t, 512, 2048);
    castT_k<<<dim3(64, 16, 8), 256, 0, stream>>>(w2, w2_t, 2048, 512);
    castT_k<<<dim3(32, 16, 1), 256, 0, stream>>>(fw, fw_t, 1024, 512);
    cast_k<<<640, 256, 0, stream>>>(ssw, sswb, 512 * 320);
    cast_k<<<640, 256, 0, stream>>>(sow, sowb, 512 * 320);

    // ---- SPT ----
    im2col_k<<<(BP_ * KP_ + 255) / 256, 256, 0, stream>>>(image, Xb);
    dim3 gspt(8, 64);
    gemm_bf16_k<<<gspt, 256, 0, stream>>>(Xb, sswb, ssb, nullptr, srct, nullptr,
                                          512, KP_, EPI_BIAS);
    ln_k<<<BP_, 256, 0, stream>>>(srct, srct, comb, ssg, ssbeta, 512, 512, 1024);
    gemm_bf16_k<<<gspt, 256, 0, stream>>>(Xb, sowb, sob, nullptr, origt, nullptr,
                                          512, KP_, EPI_BIAS);
    ln_k<<<BP_, 256, 0, stream>>>(origt, origt, comb + 512, sog, sobeta, 512,
                                  512, 1024);
    // ---- gated fusion ----
    gemm_bf16_k<<<gspt, 256, 0, stream>>>(comb, fw_t, fb, nullptr, gatelin,
                                          nullptr, 512, 1024, EPI_BIAS);
    assemble_k<<<(B_ * N_ * 128 + 255) / 256, 256, 0, stream>>>(
        gatelin, srct, origt, cls_token, pos_embed, tokens);

    // ---- transformer layers ----
    dim3 gqkv(24, 65), gproj(8, 65), gfc1(32, 65);
    for (int l = 0; l < L_; ++l) {
        const float* l1g = ln1g + l * D_;
        const float* l1b = ln1b + l * D_;
        const unsigned short* qw = qkvw_t + (size_t)l * 1536 * 512;
        const float* qb  = qkvb + (size_t)l * 3 * D_;
        const unsigned short* pw = projw_t + (size_t)l * 512 * 512;
        const float* pb  = projb + (size_t)l * D_;
        const float* tp  = temp + l * H_;
        const float* l2g = ln2g + l * D_;
        const float* l2b = ln2b + l * D_;
        const unsigned short* w1l = w1_t + (size_t)l * 2048 * 512;
        const float* b1l = b1 + (size_t)l * MLP_;
        const unsigned short* w2l = w2_t + (size_t)l * 512 * 2048;
        const float* b2l = b2 + (size_t)l * D_;

        ln_k<<<BN_, 256, 0, stream>>>(tokens, nullptr, xbuf, l1g, l1b, 512, 0,
                                      512);
        gemm_bf16_k<<<gqkv, 256, 0, stream>>>(xbuf, qw, qb, nullptr, nullptr,
                                              qkvB, 1536, 512, EPI_BIAS);
        vT_k<<<dim3(256, 5), 256, 0, stream>>>(qkvB, vt_g);
        attn_fused_k<<<dim3(256, 5), 256, 0, stream>>>(qkvB, vt_g, tp, obuf);
        gemm_bf16_k<<<gproj, 256, 0, stream>>>(obuf, pw, pb, tokens, tokens,
                                               nullptr, 512, 512, EPI_RES);
        ln_k<<<BN_, 256, 0, stream>>>(tokens, nullptr, xbuf, l2g, l2b, 512, 0,
                                      512);
        gemm_bf16_k<<<gfc1, 256, 0, stream>>>(xbuf, w1l, b1l, nullptr, nullptr,
                                              hbuf, 2048, 512, EPI_GELU);
        gemm_bf16_k<<<gproj, 256, 0, stream>>>(hbuf, w2l, b2l, tokens, tokens,
                                               nullptr, 512, 2048, EPI_RES);
    }

    // ---- final LN on cls token + head ----
    ln_k<<<B_, 256, 0, stream>>>(tokens, cls_out, nullptr, ng, nb,
                                 (long)N_ * 512, 512, 0);
    head_k<<<1, 128, 0, stream>>>(cls_out, hw, hb, out);
}

// Round 9
// 1709.926 us; speedup vs baseline: 1.6765x; 1.1454x over previous
//
#include <hip/hip_runtime.h>
#include <math.h>

// ---- problem constants ----
constexpr int B_ = 32, D_ = 512, H_ = 8, L_ = 8, MLP_ = 2048, NC_ = 3;
constexpr int P_ = 256;        // patches
constexpr int N_ = 257;        // tokens (P+1)
constexpr int HD_ = 64;        // head dim
constexpr int BP_ = B_ * P_;   // 8192 patch rows
constexpr int BN_ = B_ * N_;   // 8224 token rows
constexpr int MP_ = 8320;      // BN_ padded to 130*64
constexpr int KP_ = 320;       // 5*8*8 im2col K
constexpr int NV_ = 288;       // padded n for V^T (9 k-chunks of 32)

enum { EPI_BIAS = 0, EPI_RES = 1, EPI_GELU = 2 };

using bf16x8 = __attribute__((ext_vector_type(8))) short;
using f32x4  = __attribute__((ext_vector_type(4))) float;

__device__ __forceinline__ float b2f(unsigned short u) {
    return __uint_as_float(((unsigned)u) << 16);
}
__device__ __forceinline__ unsigned short f2b(float f) {
    unsigned u = __float_as_uint(f);
    unsigned r = (u + 0x7FFFu + ((u >> 16) & 1u)) >> 16;  // RNE
    return (unsigned short)r;
}

// ---- packed tile layout: 64x32 tiles, contiguous 4KB each, swizzle baked in.
// Element (m,k) of an [M][K] bf16 matrix lives at:
//   tile = (m>>6)*(K>>5) + (k>>5)
//   pos  = (m&63)*32 + ((((k>>3)&3) ^ (((m&63)>>1)&3))<<3) + (k&7)
// DMA of one tile = base + tid*16B, fully coalesced; LDS image == the swizzled
// image the GEMM fragment reads expect (slot s holds chunk s^swz -> read with
// quad^swz retrieves chunk quad; conflict-free, r7-verified).
__device__ __forceinline__ size_t paddr(int m, int k, int K) {
    int r = m & 63;
    int c = (k >> 3) & 3;
    return ((size_t)(m >> 6) * (K >> 5) + (k >> 5)) * 2048 + r * 32 +
           (((c ^ ((r >> 1) & 3))) << 3) + (k & 7);
}

__device__ __forceinline__ void gld_lds16(const void* g, void* l) {
    __builtin_amdgcn_global_load_lds(
        (const __attribute__((address_space(1))) void*)g,
        (__attribute__((address_space(3))) void*)l, 16, 0, 0);
}

// LDS byte-address for inline-asm ds ops (AS3 pointers are 32-bit offsets)
__device__ __forceinline__ unsigned lds_a(const void* p) {
    return (unsigned)(size_t)(const __attribute__((address_space(3))) void*)p;
}
// Opaque ds_read_b128 (rule 18): ordering fully manual.
__device__ __forceinline__ bf16x8 ds_read128(unsigned addr) {
    bf16x8 r;
    asm volatile("ds_read_b128 %0, %1" : "=v"(r) : "v"(addr));
    return r;
}

// ---------------- im2col (bf16 out, packed) ----------------
__global__ void im2col_k(const float* __restrict__ img,
                         unsigned short* __restrict__ X) {
    int idx = blockIdx.x * 256 + threadIdx.x;
    if (idx >= BP_ * KP_) return;
    int r = idx / KP_, j = idx % KP_;
    int b = r >> 8, p = r & 255;
    int py = p >> 4, px = p & 15;
    int c = j >> 6, kk = j & 63;
    int ky = kk >> 3, kx = kk & 7;
    const int dy[5] = {0, 1, -1, 1, -1};
    const int dx[5] = {0, 1, 1, -1, -1};
    int yy = (py * 8 + ky - dy[c] + 128) & 127;
    int xx = (px * 8 + kx - dx[c] + 128) & 127;
    X[paddr(r, j, KP_)] = f2b(img[b * 16384 + yy * 128 + xx]);
}

// ------- transpose + cast fp32 [K][N] -> packed bf16 B^T (N x K) -------
__global__ __launch_bounds__(256) void castT_k(const float* __restrict__ in,
                                               unsigned short* __restrict__ out,
                                               int K, int N) {
    __shared__ float t[32][33];
    size_t loff = (size_t)blockIdx.z * K * N;
    int k0 = blockIdx.x * 32, n0 = blockIdx.y * 32;
    int tx = threadIdx.x & 31, ty = threadIdx.x >> 5;
    for (int i = ty; i < 32; i += 8)
        t[i][tx] = in[loff + (size_t)(k0 + i) * N + n0 + tx];
    __syncthreads();
    for (int i = ty; i < 32; i += 8)
        out[loff + paddr(n0 + i, k0 + tx, K)] = f2b(t[tx][i]);
}

// ------- plain cast of an [N][K] fp32 matrix to packed bf16 -------
__global__ void cast_k(const float* __restrict__ in,
                       unsigned short* __restrict__ out, int n, int K) {
    int idx = blockIdx.x * 256 + threadIdx.x;
    if (idx >= n) return;
    int m = idx / K, k = idx % K;
    out[paddr(m, k, K)] = f2b(in[idx]);
}

// ---------------- bf16 MFMA GEMM: C[M,N] = A[M,K] @ Bt[N,K]^T ----------------
// Round 13: rounds 4-8 pinned fc2 at 54-57µs across 4 tile shapes and 5
// schedules — a throughput wall proportional to bytes staged (~1.25 TB/s
// effective). Cause: each gld_lds touched 16 SCATTERED 64B lines (16 rows x
// 64B at 1-4KB stride); DRAM/fabric burst efficiency ~25%. Fix: operands are
// now TILE-PACKED (64x32 tiles contiguous, swizzle baked in) so each stage is
// one 4KB burst (1 gld_lds/thread/operand at base+tid*16). LDS image and
// fragment reads identical to r8 (conflict-free). Schedule = r4's best-total:
// 3 buffers, counted vmcnt, ONE barrier/step, stage-after-reads depth-2.
__global__ __launch_bounds__(256, 6) void gemm_bf16_k(
    const unsigned short* __restrict__ A, const unsigned short* __restrict__ Bt,
    const float* __restrict__ bias, const float* __restrict__ res,
    float* __restrict__ outF, unsigned short* __restrict__ outB,
    int Nn, int K, int epi, int packB) {
    constexpr int BK = 32;
    constexpr int TSZ = 64 * BK * 2;            // 4096 B per tile buffer
    __shared__ unsigned short As[3][64 * BK];   // 3 x 4 KiB
    __shared__ unsigned short Bs[3][64 * BK];   // 3 x 4 KiB (24 KiB total)
    int tid = threadIdx.x, lane = tid & 63;
    int wave = tid >> 6;
    int wrow = (wave >> 1) * 32, wcol = (wave & 1) * 32;

    // XCD-chunked bijective remap: each XCD gets a contiguous run of tiles.
    int gx = gridDim.x;
    int nwg = gx * (int)gridDim.y;
    int lid = blockIdx.y * gx + blockIdx.x;
    int qq = nwg >> 3, rr = nwg & 7;
    int xcd = lid & 7, loc = lid >> 3;
    int sid = (xcd < rr ? xcd * (qq + 1) : rr * (qq + 1) + (xcd - rr) * qq) + loc;
    size_t bm = (size_t)(sid / gx) * 64, bn = (size_t)(sid % gx) * 64;

    int KT = K >> 5;  // k-tiles
    const unsigned short* Ab = A + (size_t)(bm >> 6) * KT * 2048;
    const unsigned short* Bb = Bt + (size_t)(bn >> 6) * KT * 2048;

    f32x4 acc[2][2] = {};
    int quad = lane >> 4, col = lane & 15;
    int NT = KT;

    unsigned aB0 = lds_a(&As[0][0]);
    unsigned bB0 = lds_a(&Bs[0][0]);
    // fragment byte offsets (conflict-free swizzle, matches packed image)
    unsigned aoff[2], boff[2];
#pragma unroll
    for (int i = 0; i < 2; ++i) {
        int ra = wrow + i * 16 + col;
        int rb = wcol + i * 16 + col;
        aoff[i] = ra * (BK * 2) + ((quad ^ ((ra >> 1) & 3)) << 4);
        boff[i] = rb * (BK * 2) + ((quad ^ ((rb >> 1) & 3)) << 4);
    }

    // stage one packed 64x32 tile pair: 2 contiguous 4KB bursts.
    auto stage = [&](int buf, int t_) {
        const unsigned short* as = Ab + (size_t)t_ * 2048 + tid * 8;
        const unsigned short* bs = Bb + (size_t)t_ * 2048 + tid * 8;
        gld_lds16(as, (char*)As[0] + buf * TSZ + tid * 16);
        gld_lds16(bs, (char*)Bs[0] + buf * TSZ + tid * 16);
    };

    stage(0, 0);
    if (NT > 1) stage(1, 1);
    for (int t = 0; t < NT; ++t) {
        int cur = t % 3;
        if (t + 1 < NT)
            asm volatile("s_waitcnt vmcnt(2)" ::: "memory");  // tile t landed
        else
            asm volatile("s_waitcnt vmcnt(0)" ::: "memory");
        __builtin_amdgcn_s_barrier();
        __builtin_amdgcn_sched_barrier(0);
        unsigned aB = aB0 + cur * TSZ;
        unsigned bB = bB0 + cur * TSZ;
        bf16x8 af[2], bfr[2];
#pragma unroll
        for (int i = 0; i < 2; ++i) {
            af[i]  = ds_read128(aB + aoff[i]);
            bfr[i] = ds_read128(bB + boff[i]);
        }
        if (t + 2 < NT) stage((t + 2) % 3, t + 2);  // depth-2, post-reads
        asm volatile("s_waitcnt lgkmcnt(0)" ::: "memory");
        __builtin_amdgcn_sched_barrier(0);
#pragma unroll
        for (int mi = 0; mi < 2; ++mi)
#pragma unroll
            for (int ni = 0; ni < 2; ++ni)
                acc[mi][ni] = __builtin_amdgcn_mfma_f32_16x16x32_bf16(
                    af[mi], bfr[ni], acc[mi][ni], 0, 0, 0);
        __builtin_amdgcn_sched_barrier(0);  // pin reads+MFMA inside the iter
    }

#pragma unroll
    for (int mi = 0; mi < 2; ++mi) {
#pragma unroll
        for (int ni = 0; ni < 2; ++ni) {
            size_t gm0 = bm + wrow + mi * 16 + quad * 4;
            size_t gn = bn + wcol + ni * 16 + col;
            float bs = bias ? bias[gn] : 0.f;
#pragma unroll
            for (int r = 0; r < 4; ++r) {
                size_t o = (gm0 + r) * Nn + gn;
                float v = acc[mi][ni][r] + bs;
                if (epi == EPI_GELU)
                    v = 0.5f * v * (1.f + erff(v * 0.70710678118654752f));
                else if (epi == EPI_RES)
                    v += res[o];
                if (outF) outF[o] = v;
                if (outB) {
                    size_t ob = packB ? paddr((int)(gm0 + r), (int)gn, Nn) : o;
                    outB[ob] = f2b(v);
                }
            }
        }
    }
}

// ------- LayerNorm D=512, fp32 out + packed-bf16 out (shuffle-reduce) -------
__global__ __launch_bounds__(256) void ln_k(
    const float* __restrict__ in, float* __restrict__ outF,
    unsigned short* __restrict__ outB, const float* __restrict__ g,
    const float* __restrict__ be, long instride, long ofs, int kTot, int kOff) {
    __shared__ float red[8];
    int row = blockIdx.x;
    const float2* x = (const float2*)(in + (size_t)row * instride);
    int t = threadIdx.x, lane = t & 63, wv = t >> 6;
    float2 v = x[t];
    float s = v.x + v.y;
#pragma unroll
    for (int m = 1; m < 64; m <<= 1) s += __shfl_xor(s, m);
    if (lane == 0) red[wv] = s;
    __syncthreads();
    float mu = (red[0] + red[1] + red[2] + red[3]) * (1.f / 512.f);
    float d0 = v.x - mu, d1 = v.y - mu;
    float q = d0 * d0 + d1 * d1;
#pragma unroll
    for (int m = 1; m < 64; m <<= 1) q += __shfl_xor(q, m);
    if (lane == 0) red[4 + wv] = q;
    __syncthreads();
    float rs =
        rsqrtf((red[4] + red[5] + red[6] + red[7]) * (1.f / 512.f) + 1e-5f);
    float2 gg = ((const float2*)g)[t];
    float2 bb = ((const float2*)be)[t];
    float y0 = d0 * rs * gg.x + bb.x;
    float y1 = d1 * rs * gg.y + bb.y;
    if (outF) {
        float2* y = (float2*)(outF + (size_t)row * ofs);
        y[t] = make_float2(y0, y1);
    }
    if (outB) {
        unsigned int p = (unsigned)f2b(y0) | ((unsigned)f2b(y1) << 16);
        size_t a = paddr(row, kOff + 2 * t, kTot);  // k even -> 4B aligned
        *(unsigned int*)(outB + a) = p;
    }
}

// ------- gate sigmoid + fuse + cls + pos_embed -> tokens (fp32, float4) -------
__global__ void assemble_k(const float* __restrict__ gatelin,
                           const float* __restrict__ src,
                           const float* __restrict__ orig,
                           const float* __restrict__ cls,
                           const float* __restrict__ pos,
                           float* __restrict__ tokens) {
    int idx = blockIdx.x * 256 + threadIdx.x;  // float4 granularity
    if (idx >= B_ * N_ * 128) return;
    int d4 = idx & 127;
    int bn = idx >> 7;
    int b = bn / N_, n = bn % N_;
    float4 pv = ((const float4*)pos)[n * 128 + d4];
    float4 v;
    if (n == 0) {
        v = ((const float4*)cls)[d4];
    } else {
        int r = b * 256 + (n - 1);
        float4 gl = ((const float4*)gatelin)[r * 128 + d4];
        float4 sv = ((const float4*)src)[r * 128 + d4];
        float4 ov = ((const float4*)orig)[r * 128 + d4];
        float g0 = 1.f / (1.f + expf(-gl.x));
        float g1 = 1.f / (1.f + expf(-gl.y));
        float g2 = 1.f / (1.f + expf(-gl.z));
        float g3 = 1.f / (1.f + expf(-gl.w));
        v.x = g0 * sv.x + (1.f - g0) * ov.x;
        v.y = g1 * sv.y + (1.f - g1) * ov.y;
        v.z = g2 * sv.z + (1.f - g2) * ov.z;
        v.w = g3 * sv.w + (1.f - g3) * ov.w;
    }
    v.x += pv.x; v.y += pv.y; v.z += pv.z; v.w += pv.w;
    ((float4*)tokens)[idx] = v;
}

// ---------------- V transpose: qkv -> Vt_g[bh][64][NV_] ----------------
__global__ __launch_bounds__(256) void vT_k(const unsigned short* __restrict__ qkv,
                                            unsigned short* __restrict__ Vt_g) {
    __shared__ unsigned short t[64][72];
    int bh = blockIdx.x, nt = blockIdx.y;
    int b = bh >> 3, h = bh & 7;
    int n0 = nt * 64;
    const unsigned short* vb = qkv + (size_t)(b * N_) * 1536 + 1024 + h * 64;
    int tid = threadIdx.x;
    for (int idx = tid; idx < 64 * 8; idx += 256) {
        int n = idx >> 3, c = idx & 7;
        int gn = n0 + n;
        uint4 u = {0, 0, 0, 0};
        if (gn < N_) u = *(const uint4*)(vb + (size_t)gn * 1536 + c * 8);
        *(uint4*)&t[n][c * 8] = u;
    }
    __syncthreads();
    for (int idx = tid; idx < 64 * 8; idx += 256) {
        int d = idx >> 3, j = idx & 7;
        if (n0 + j * 8 >= NV_) continue;
        unsigned short tmp[8];
#pragma unroll
        for (int e = 0; e < 8; ++e) tmp[e] = t[j * 8 + e][d];
        *(uint4*)&Vt_g[((size_t)bh * 64 + d) * NV_ + n0 + j * 8] =
            *(uint4*)tmp;
    }
}

// ---------------- fused flash attention v3: one wave per q-tile --------------
__global__ __launch_bounds__(256) void attn_fused_k(
    const unsigned short* __restrict__ qkv,
    const unsigned short* __restrict__ Vt_g, const float* __restrict__ temp,
    unsigned short* __restrict__ obuf) {
    __shared__ __align__(16) unsigned short Ps[4][16][40];
    int bh = blockIdx.x;
    int b = bh >> 3, h = bh & 7;
    int tid = threadIdx.x, lane = tid & 63, wave = tid >> 6;
    int quad = lane >> 4, cid = lane & 15;
    int qt = blockIdx.y * 4 + wave;
    if (qt > 16) return;
    const unsigned short* qb = qkv + (size_t)(b * N_) * 1536 + h * 64;
    const unsigned short* kb = qb + 512;
    const unsigned short* vt = Vt_g + (size_t)bh * 64 * NV_;
    float tmp = temp[h];

    int qrow = qt * 16 + cid;
    if (qrow > 256) qrow = 256;
    bf16x8 aq0 = *(const bf16x8*)(qb + (size_t)qrow * 1536 + quad * 8);
    bf16x8 aq1 = *(const bf16x8*)(qb + (size_t)qrow * 1536 + 32 + quad * 8);

    f32x4 s[18];
#pragma unroll
    for (int t = 0; t < 17; ++t) {
        int krow = t * 16 + cid;
        if (t == 16 && krow > 256) krow = 256;  // static after full unroll
        const unsigned short* kp = kb + (size_t)krow * 1536 + quad * 8;
        bf16x8 bk0 = *(const bf16x8*)kp;
        bf16x8 bk1 = *(const bf16x8*)(kp + 32);
        f32x4 a = {0.f, 0.f, 0.f, 0.f};
        a = __builtin_amdgcn_mfma_f32_16x16x32_bf16(aq0, bk0, a, 0, 0, 0);
        a = __builtin_amdgcn_mfma_f32_16x16x32_bf16(aq1, bk1, a, 0, 0, 0);
        s[t] = a;
    }

    // mask + row max (rows = qt*16 + quad*4 + r, cols = t*16 + cid)
    float mx[4] = {-1e30f, -1e30f, -1e30f, -1e30f};
#pragma unroll
    for (int t = 0; t < 17; ++t) {
        int col = t * 16 + cid;
#pragma unroll
        for (int r = 0; r < 4; ++r) {
            int row = qt * 16 + quad * 4 + r;
            float v = s[t][r] * tmp;
            if (col == row || col >= 257) v = -1e30f;
            s[t][r] = v;
            mx[r] = fmaxf(mx[r], v);
        }
    }
    s[17] = f32x4{-1e30f, -1e30f, -1e30f, -1e30f};
#pragma unroll
    for (int m = 1; m < 16; m <<= 1)
#pragma unroll
        for (int r = 0; r < 4; ++r) mx[r] = fmaxf(mx[r], __shfl_xor(mx[r], m));
    float sum[4] = {0.f, 0.f, 0.f, 0.f};
#pragma unroll
    for (int t = 0; t < 18; ++t)
#pragma unroll
        for (int r = 0; r < 4; ++r) {
            float e = __expf(s[t][r] - mx[r]);
            float ef = b2f(f2b(e));
            s[t][r] = ef;
            sum[r] += ef;
        }
#pragma unroll
    for (int m = 1; m < 16; m <<= 1)
#pragma unroll
        for (int r = 0; r < 4; ++r) sum[r] += __shfl_xor(sum[r], m);
    float inv[4];
#pragma unroll
    for (int r = 0; r < 4; ++r) inv[r] = 1.f / sum[r];

    // PV: 9 k-chunks of 32 over n (fully unrolled, s[] stays in VGPRs)
    f32x4 o[4] = {};
#pragma unroll
    for (int kt = 0; kt < 9; ++kt) {
#pragma unroll
        for (int hh = 0; hh < 2; ++hh) {
            int t = kt * 2 + hh;
#pragma unroll
            for (int r = 0; r < 4; ++r)
                Ps[wave][quad * 4 + r][hh * 16 + cid] = f2b(s[t][r]);
        }
        bf16x8 ap = *(const bf16x8*)&Ps[wave][cid][quad * 8];
#pragma unroll
        for (int dt = 0; dt < 4; ++dt) {
            bf16x8 bv = *(const bf16x8*)(vt + (size_t)(dt * 16 + cid) * NV_ +
                                         kt * 32 + quad * 8);
            o[dt] =
                __builtin_amdgcn_mfma_f32_16x16x32_bf16(ap, bv, o[dt], 0, 0, 0);
        }
    }
#pragma unroll
    for (int dt = 0; dt < 4; ++dt)
#pragma unroll
        for (int r = 0; r < 4; ++r) {
            int row = qt * 16 + quad * 4 + r;
            if (row < N_)
                obuf[paddr(b * N_ + row, h * 64 + dt * 16 + cid, 512)] =
                    f2b(o[dt][r] * inv[r]);
        }
}

// ------- head (fp32, tiny) -------
__global__ void head_k(const float* __restrict__ cls_out,
                       const float* __restrict__ hw,
                       const float* __restrict__ hb, float* __restrict__ out) {
    int t = threadIdx.x;
    if (t >= B_ * NC_) return;
    int b = t / NC_, c = t % NC_;
    float acc = hb[c];
    for (int d = 0; d < D_; ++d) acc += cls_out[b * D_ + d] * hw[d * NC_ + c];
    out[t] = acc;
}

extern "C" void kernel_launch(void* const* d_in, const int* in_sizes, int n_in,
                              void* d_out, int out_size, void* d_ws,
                              size_t ws_size, hipStream_t stream) {
    const float* image     = (const float*)d_in[0];
    const float* ssw       = (const float*)d_in[1];
    const float* ssb       = (const float*)d_in[2];
    const float* ssg       = (const float*)d_in[3];
    const float* ssbeta    = (const float*)d_in[4];
    const float* sow       = (const float*)d_in[5];
    const float* sob       = (const float*)d_in[6];
    const float* sog       = (const float*)d_in[7];
    const float* sobeta    = (const float*)d_in[8];
    const float* fw        = (const float*)d_in[9];
    const float* fb        = (const float*)d_in[10];
    const float* cls_token = (const float*)d_in[11];
    const float* pos_embed = (const float*)d_in[12];
    const float* ln1g      = (const float*)d_in[13];
    const float* ln1b      = (const float*)d_in[14];
    const float* qkvw      = (const float*)d_in[15];
    const float* qkvb      = (const float*)d_in[16];
    const float* projw     = (const float*)d_in[17];
    const float* projb     = (const float*)d_in[18];
    const float* temp      = (const float*)d_in[19];
    const float* ln2g      = (const float*)d_in[20];
    const float* ln2b      = (const float*)d_in[21];
    const float* w1        = (const float*)d_in[22];
    const float* b1        = (const float*)d_in[23];
    const float* w2        = (const float*)d_in[24];
    const float* b2        = (const float*)d_in[25];
    const float* ng        = (const float*)d_in[26];
    const float* nb        = (const float*)d_in[27];
    const float* hw        = (const float*)d_in[28];
    const float* hb        = (const float*)d_in[29];
    float* out = (float*)d_out;

    char* w = (char*)d_ws;
    size_t off = 0;
    float* tokens = (float*)w;                           off += (size_t)MP_ * 512 * 4;
    unsigned short* qkvw_t = (unsigned short*)(w + off); off += (size_t)8 * 1536 * 512 * 2;
    unsigned short* projw_t = (unsigned short*)(w + off); off += (size_t)8 * 512 * 512 * 2;
    unsigned short* w1_t = (unsigned short*)(w + off);   off += (size_t)8 * 2048 * 512 * 2;
    unsigned short* w2_t = (unsigned short*)(w + off);   off += (size_t)8 * 512 * 2048 * 2;
    unsigned short* fw_t = (unsigned short*)(w + off);   off += (size_t)512 * 1024 * 2;
    unsigned short* sswb = (unsigned short*)(w + off);   off += (size_t)512 * 320 * 2;
    unsigned short* sowb = (unsigned short*)(w + off);   off += (size_t)512 * 320 * 2;
    char* S = w + off;

    // prestage aliases (dead after assemble_k)
    unsigned short* Xb   = (unsigned short*)S;
    float* srct          = (float*)(S + 5242880);
    float* origt         = (float*)(S + 5242880 + 16777216);
    unsigned short* comb = (unsigned short*)(S + 5242880 + 2 * 16777216);
    float* gatelin       = (float*)(S + 5242880 + 3 * 16777216);

    // per-layer aliases
    unsigned short* xbuf = (unsigned short*)S;                      // 8,519,680
    unsigned short* qkvB = (unsigned short*)(S + 8519680);          // 25,559,040
    unsigned short* obuf = (unsigned short*)(S + 8519680 + 25559040);            // 8,519,680
    unsigned short* hbuf = (unsigned short*)(S + 8519680 + 25559040 + 8519680);  // 34,078,720
    unsigned short* vt_g = (unsigned short*)(S + 8519680 + 25559040 + 8519680 +
                                             34078720);             // 9,437,184
    float* cls_out = (float*)(S + 8519680 + 25559040 + 8519680 + 34078720 +
                              9437184);

    // ---- weight casts/transposes (packed bf16 B^T) ----
    castT_k<<<dim3(16, 48, 8), 256, 0, stream>>>(qkvw, qkvw_t, 512, 1536);
    castT_k<<<dim3(16, 16, 8), 256, 0, stream>>>(projw, projw_t, 512, 512);
    castT_k<<<dim3(16, 64, 8), 256, 0, stream>>>(w1, w1_t, 512, 2048);
    castT_k<<<dim3(64, 16, 8), 256, 0, stream>>>(w2, w2_t, 2048, 512);
    castT_k<<<dim3(32, 16, 1), 256, 0, stream>>>(fw, fw_t, 1024, 512);
    cast_k<<<640, 256, 0, stream>>>(ssw, sswb, 512 * 320, 320);
    cast_k<<<640, 256, 0, stream>>>(sow, sowb, 512 * 320, 320);

    // ---- SPT ----
    im2col_k<<<(BP_ * KP_ + 255) / 256, 256, 0, stream>>>(image, Xb);
    dim3 gspt(8, 128);
    gemm_bf16_k<<<gspt, 256, 0, stream>>>(Xb, sswb, ssb, nullptr, srct, nullptr,
                                          512, KP_, EPI_BIAS, 0);
    ln_k<<<BP_, 256, 0, stream>>>(srct, srct, comb, ssg, ssbeta, 512, 512,
                                  1024, 0);
    gemm_bf16_k<<<gspt, 256, 0, stream>>>(Xb, sowb, sob, nullptr, origt, nullptr,
                                          512, KP_, EPI_BIAS, 0);
    ln_k<<<BP_, 256, 0, stream>>>(origt, origt, comb, sog, sobeta, 512, 512,
                                  1024, 512);
    // ---- gated fusion ----
    gemm_bf16_k<<<gspt, 256, 0, stream>>>(comb, fw_t, fb, nullptr, gatelin,
                                          nullptr, 512, 1024, EPI_BIAS, 0);
    assemble_k<<<(B_ * N_ * 128 + 255) / 256, 256, 0, stream>>>(
        gatelin, srct, origt, cls_token, pos_embed, tokens);

    // ---- transformer layers ----
    dim3 gqkv(24, 130), gproj(8, 130), gfc1(32, 130);
    for (int l = 0; l < L_; ++l) {
        const float* l1g = ln1g + l * D_;
        const float* l1b = ln1b + l * D_;
        const unsigned short* qw = qkvw_t + (size_t)l * 1536 * 512;
        const float* qb  = qkvb + (size_t)l * 3 * D_;
        const unsigned short* pw = projw_t + (size_t)l * 512 * 512;
        const float* pb  = projb + (size_t)l * D_;
        const float* tp  = temp + l * H_;
        const float* l2g = ln2g + l * D_;
        const float* l2b = ln2b + l * D_;
        const unsigned short* w1l = w1_t + (size_t)l * 2048 * 512;
        const float* b1l = b1 + (size_t)l * MLP_;
        const unsigned short* w2l = w2_t + (size_t)l * 512 * 2048;
        const float* b2l = b2 + (size_t)l * D_;

        ln_k<<<BN_, 256, 0, stream>>>(tokens, nullptr, xbuf, l1g, l1b, 512, 0,
                                      512, 0);
        gemm_bf16_k<<<gqkv, 256, 0, stream>>>(xbuf, qw, qb, nullptr, nullptr,
                                              qkvB, 1536, 512, EPI_BIAS, 0);
        vT_k<<<dim3(256, 5), 256, 0, stream>>>(qkvB, vt_g);
        attn_fused_k<<<dim3(256, 5), 256, 0, stream>>>(qkvB, vt_g, tp, obuf);
        gemm_bf16_k<<<gproj, 256, 0, stream>>>(obuf, pw, pb, tokens, tokens,
                                               nullptr, 512, 512, EPI_RES, 0);
        ln_k<<<BN_, 256, 0, stream>>>(tokens, nullptr, xbuf, l2g, l2b, 512, 0,
                                      512, 0);
        gemm_bf16_k<<<gfc1, 256, 0, stream>>>(xbuf, w1l, b1l, nullptr, nullptr,
                                              hbuf, 2048, 512, EPI_GELU, 1);
        gemm_bf16_k<<<gproj, 256, 0, stream>>>(hbuf, w2l, b2l, tokens, tokens,
                                               nullptr, 512, 2048, EPI_RES, 0);
    }

    // ---- final LN on cls token + head ----
    ln_k<<<B_, 256, 0, stream>>>(tokens, cls_out, nullptr, ng, nb,
                                 (long)N_ * 512, 512, 512, 0);
    head_k<<<1, 128, 0, stream>>>(cls_out, hw, hb, out);
}